// Round 15
// baseline (19654.182 us; speedup 1.0000x reference)
//
#include <hip/hip_runtime.h>
#include <cstdint>

#define SQ 4096
#define FD 256
#define HD 512
#define GD 2048

// workspace layout (float elements)
#define WS_X       0                         // x [4096][512]
#define WS_XPROJ   (WS_X + SQ*HD)            // xproj [2][4096][2048]
#define WS_WT      (WS_XPROJ + 2*SQ*GD)      // conv_w transposed [2][256][256]
#define WS_LINT    (WS_WT + 2*FD*FD)         // lin_w transposed [256][256]
#define WS_SYNC    (WS_LINT + FD*FD)         // payload: u64[2 dir][2 slot][512] = 16 KB

typedef __attribute__((ext_vector_type(4))) float f32x4;
typedef unsigned long long u64;

__device__ __forceinline__ float sigf(float x) { return 1.f / (1.f + __expf(-x)); }
// tanh(x) = 2*sigmoid(2x) - 1  (one __expf; |err| ~1e-7)
__device__ __forceinline__ float tanh_s(float x) { return fmaf(2.f, sigf(2.f * x), -1.f); }

#define REP8(M) M(0)M(1)M(2)M(3)M(4)M(5)M(6)M(7)

// ---------------- prep: transpose small weights, zero sync payload ----------------
__global__ __launch_bounds__(256) void prep_kernel(const float* __restrict__ conv_w,
                                                   const float* __restrict__ lin_w,
                                                   float* __restrict__ Wt,
                                                   float* __restrict__ linT,
                                                   float* __restrict__ sync) {
  int n = blockIdx.x * 256 + threadIdx.x;
  if (n < 4096) sync[n] = 0.f;               // 16 KB payload (tags := 0)
  if (n < 2 * FD * FD) {
    int o = n & 255, f = (n >> 8) & 255, k = n >> 16;
    Wt[n] = conv_w[o * 512 + k * 256 + f];   // Wt[k][f][o]
  } else {
    int m = n - 2 * FD * FD;
    int o = m & 255, f = m >> 8;
    linT[m] = lin_w[o * 256 + f];            // linT[f][o]
  }
}

// ---------------- char CNN + concat into x ----------------
__global__ __launch_bounds__(256) void charcnn_kernel(const float* __restrict__ wemb,
    const int* __restrict__ cidx, const float* __restrict__ cemb,
    const float* __restrict__ Wt, const float* __restrict__ conv_b,
    const float* __restrict__ linT, const float* __restrict__ lin_b,
    float* __restrict__ x) {
  __shared__ float ceT[256][20];
  __shared__ float pooled[256];
  int s = blockIdx.x, o = threadIdx.x;
  #pragma unroll
  for (int l = 0; l < 16; ++l) {
    int idx = cidx[s * 16 + l];
    ceT[o][l] = cemb[idx * 256 + o];
  }
  __syncthreads();
  float acc[15];
  float cb = conv_b[o];
  #pragma unroll
  for (int l = 0; l < 15; ++l) acc[l] = cb;
  for (int f = 0; f < 256; ++f) {
    float w0 = Wt[f * 256 + o];
    float w1 = Wt[65536 + f * 256 + o];
    float4 ca = *(const float4*)&ceT[f][0];
    float4 cv = *(const float4*)&ceT[f][4];
    float4 cc = *(const float4*)&ceT[f][8];
    float4 cd = *(const float4*)&ceT[f][12];
    float c[16] = {ca.x, ca.y, ca.z, ca.w, cv.x, cv.y, cv.z, cv.w,
                   cc.x, cc.y, cc.z, cc.w, cd.x, cd.y, cd.z, cd.w};
    #pragma unroll
    for (int l = 0; l < 15; ++l) acc[l] += c[l] * w0 + c[l + 1] * w1;
  }
  float m = 0.f;
  #pragma unroll
  for (int l = 0; l < 15; ++l) m = fmaxf(m, acc[l]);
  pooled[o] = m;
  __syncthreads();
  float a2 = lin_b[o];
  for (int f = 0; f < 256; f += 4) {
    float4 p = *(const float4*)&pooled[f];
    a2 += p.x * linT[(f + 0) * 256 + o] + p.y * linT[(f + 1) * 256 + o]
        + p.z * linT[(f + 2) * 256 + o] + p.w * linT[(f + 3) * 256 + o];
  }
  x[(size_t)s * 512 + o] = wemb[(size_t)s * 256 + o];
  x[(size_t)s * 512 + 256 + o] = a2;
}

// ---------------- input projection GEMM ----------------
__global__ __launch_bounds__(256) void xproj_kernel(const float* __restrict__ x,
    const float* __restrict__ Wih_f, const float* __restrict__ Wih_r,
    const float* __restrict__ bih_f, const float* __restrict__ bhh_f,
    const float* __restrict__ bih_r, const float* __restrict__ bhh_r,
    float* __restrict__ xproj) {
  __shared__ float As[64][33];
  __shared__ float Bs[64][33];
  int dir = blockIdx.z;
  const float* B  = dir ? Wih_r : Wih_f;
  const float* b1 = dir ? bih_r : bih_f;
  const float* b2 = dir ? bhh_r : bhh_f;
  int m0 = blockIdx.x * 64, n0 = blockIdx.y * 64;
  int tid = threadIdx.x, tx = tid & 15, ty = tid >> 4;
  float acc[4][4];
  #pragma unroll
  for (int j = 0; j < 4; ++j) {
    float bias = b1[n0 + tx * 4 + j] + b2[n0 + tx * 4 + j];
    #pragma unroll
    for (int i = 0; i < 4; ++i) acc[i][j] = bias;
  }
  int lc = tid & 31, lr0 = tid >> 5;
  for (int k0 = 0; k0 < 512; k0 += 32) {
    #pragma unroll
    for (int i = 0; i < 8; ++i) {
      As[lr0 + 8 * i][lc] = x[(size_t)(m0 + lr0 + 8 * i) * 512 + k0 + lc];
      Bs[lr0 + 8 * i][lc] = B[(size_t)(n0 + lr0 + 8 * i) * 512 + k0 + lc];
    }
    __syncthreads();
    #pragma unroll
    for (int kk = 0; kk < 32; ++kk) {
      float a0 = As[ty * 4 + 0][kk], a1 = As[ty * 4 + 1][kk];
      float a2 = As[ty * 4 + 2][kk], a3 = As[ty * 4 + 3][kk];
      float q0 = Bs[tx * 4 + 0][kk], q1 = Bs[tx * 4 + 1][kk];
      float q2 = Bs[tx * 4 + 2][kk], q3 = Bs[tx * 4 + 3][kk];
      acc[0][0] += a0 * q0; acc[0][1] += a0 * q1; acc[0][2] += a0 * q2; acc[0][3] += a0 * q3;
      acc[1][0] += a1 * q0; acc[1][1] += a1 * q1; acc[1][2] += a1 * q2; acc[1][3] += a1 * q3;
      acc[2][0] += a2 * q0; acc[2][1] += a2 * q1; acc[2][2] += a2 * q2; acc[2][3] += a2 * q3;
      acc[3][0] += a3 * q0; acc[3][1] += a3 * q1; acc[3][2] += a3 * q2; acc[3][3] += a3 * q3;
    }
    __syncthreads();
  }
  size_t base = (size_t)dir * SQ * GD;
  #pragma unroll
  for (int i = 0; i < 4; ++i) {
    float4 v = make_float4(acc[i][0], acc[i][1], acc[i][2], acc[i][3]);
    *(float4*)&xproj[base + (size_t)(m0 + ty * 4 + i) * GD + n0 + tx * 4] = v;
  }
}

// ---------------- persistent bidirectional LSTM recurrence ----------------
// r14 structure (measured best: 6.66 ms steady) + ONE change: the 8 weight
// f32x4 loads and the xval load are issued via inline asm AT LOOP TOP (before
// the poll), so their L2/L3 latency (~300/~600 cy) hides under the poll +
// barrier instead of sitting on the post-barrier critical path (r14's VGPR=40
// proved the compiler sinks them after the barrier). Explicit
// s_waitcnt vmcnt(0) + sched_barrier(0) after the barrier (compiler does not
// track asm loads; rule #18 prevents FMA hoisting above the wait).
// Everything else identical to r14 -- protocol (one u64 per h per slot =
// (tag<<32)|h_bits, double slot, monotone tags, RMW publish), wave mapping
// (wave w owns h j=w; lane = gate*16+kq), single barrier, LDS dbuf; safety
// proofs in r14 comments carry verbatim.
__global__ __launch_bounds__(1024, 4) void lstm_kernel(const float* __restrict__ xproj,
    const float* __restrict__ Whh_f, const float* __restrict__ Whh_r,
    u64* __restrict__ payu, float* __restrict__ out) {
  __shared__ float hl[2][16 * 36];   // double-buffered h: 16 kq-slices of 32, pitch 36
  int dir = blockIdx.x >> 5;
  int wid = blockIdx.x & 31;
  int hbase = wid * 16;
  int tid = threadIdx.x;
  int w = tid >> 6, lane = tid & 63;
  int gate = lane >> 4, kq = lane & 15;
  int Rrow = (gate << 9) + hbase + w;              // gate*512 + hbase + j(=w)
  const float* Whh = dir ? Whh_r : Whh_f;
  const float* xp = xproj + (size_t)dir * SQ * GD;
  const f32x4* wsrc4 = (const f32x4*)(Whh + (size_t)Rrow * 512 + kq * 32);
  u64* mypay = payu + (size_t)dir * 1024;          // [slot][512]

  const bool lz = (lane == 0);                     // gate lane of wave w
  float cst = 0.f, hlast = 0.f;

  for (int t = 0; t < SQ; ++t) {
    int p = dir ? (SQ - 1 - t) : t;
    // ---- prefetch: issue weight + xval loads BEFORE the poll (asm: cannot
    // be sunk). Latency overlaps poll + barrier. ----
    f32x4 w0, w1, w2, w3, w4, w5, w6, w7;
    asm volatile(
      "global_load_dwordx4 %0, %8, off\n\t"
      "global_load_dwordx4 %1, %8, off offset:16\n\t"
      "global_load_dwordx4 %2, %8, off offset:32\n\t"
      "global_load_dwordx4 %3, %8, off offset:48\n\t"
      "global_load_dwordx4 %4, %8, off offset:64\n\t"
      "global_load_dwordx4 %5, %8, off offset:80\n\t"
      "global_load_dwordx4 %6, %8, off offset:96\n\t"
      "global_load_dwordx4 %7, %8, off offset:112"
      : "=v"(w0), "=v"(w1), "=v"(w2), "=v"(w3),
        "=v"(w4), "=v"(w5), "=v"(w6), "=v"(w7)
      : "v"(wsrc4));
    float xval;
    const float* xaddr = xp + (size_t)p * GD + Rrow;
    asm volatile("global_load_dword %0, %1, off" : "=v"(xval) : "v"(xaddr));

    int buf = (t + 1) & 1;                         // stage h(t-1) into this buf
    if (tid < 512) {                               // stager: one u64 word each
      float hv;
      if (t == 0) hv = 0.f;
      else {
        const u64* src = mypay + ((t - 1) & 1) * 512 + tid;
        unsigned tg = (unsigned)t;
        u64 v;
        do { v = __hip_atomic_load(src, __ATOMIC_RELAXED, __HIP_MEMORY_SCOPE_AGENT); }
        while ((unsigned)(v >> 32) != tg);
        hv = __uint_as_float((unsigned)v);
      }
      hl[buf][(tid >> 5) * 36 + (tid & 31)] = hv;
    }
    __syncthreads();                               // h ready (sole barrier)
    asm volatile("s_waitcnt vmcnt(0)" ::: "memory"); // asm loads complete
    __builtin_amdgcn_sched_barrier(0);             // no FMA hoisting above
    float a0 = 0.f, a1 = 0.f, a2 = 0.f, a3 = 0.f;
    const f32x4* hq4 = (const f32x4*)&hl[buf][kq * 36];
#define GST(i) { f32x4 hh = hq4[i]; \
    a0 = fmaf(w##i[0], hh[0], a0); a1 = fmaf(w##i[1], hh[1], a1); \
    a2 = fmaf(w##i[2], hh[2], a2); a3 = fmaf(w##i[3], hh[3], a3); }
    REP8(GST)
#undef GST
    float acc = (a0 + a1) + (a2 + a3);
    acc += __shfl_xor(acc, 1);                     // kq reduce (16 lanes)
    acc += __shfl_xor(acc, 2);
    acc += __shfl_xor(acc, 4);
    acc += __shfl_xor(acc, 8);
    float gx = acc + xval;                         // valid at kq==0 lanes
    // parallel activation at the 4 kq==0 lanes (gate 2 = tanh, else sigmoid)
    float act = (gate == 2) ? tanh_s(gx) : sigf(gx);
    float aI = __shfl(act, 0);                     // in-wave gather (full wave)
    float aF = __shfl(act, 16);
    float aG = __shfl(act, 32);
    float aO = __shfl(act, 48);
    if (lz) {
      float c = aF * cst + aI * aG;
      float hval = aO * tanh_s(c);
      cst = c; hlast = hval;
      // publish FIRST (RMW executes at coherence point), then output store
      u64 word = ((u64)(unsigned)(t + 1) << 32) | __float_as_uint(hval);
      u64 old = __hip_atomic_exchange(mypay + (t & 1) * 512 + hbase + w, word,
                                      __ATOMIC_RELAXED, __HIP_MEMORY_SCOPE_AGENT);
      asm volatile("" :: "v"(old));
      out[(size_t)p * 1024 + dir * 512 + hbase + w] = hval;
    }
  }
  if (lz) {
    size_t OH = (size_t)SQ * 1024;
    out[OH + dir * 512 + hbase + w] = hlast;       // hidden
    out[OH + 1024 + dir * 512 + hbase + w] = cst;  // cell
  }
}

extern "C" void kernel_launch(void* const* d_in, const int* in_sizes, int n_in,
                              void* d_out, int out_size, void* d_ws, size_t ws_size,
                              hipStream_t stream) {
  const float* wemb   = (const float*)d_in[0];
  const int*   cidx   = (const int*)d_in[1];
  const float* cemb   = (const float*)d_in[2];
  const float* conv_w = (const float*)d_in[3];
  const float* conv_b = (const float*)d_in[4];
  const float* lin_w  = (const float*)d_in[5];
  const float* lin_b  = (const float*)d_in[6];
  const float* Wih_f  = (const float*)d_in[7];
  const float* Whh_f  = (const float*)d_in[8];
  const float* bih_f  = (const float*)d_in[9];
  const float* bhh_f  = (const float*)d_in[10];
  const float* Wih_r  = (const float*)d_in[11];
  const float* Whh_r  = (const float*)d_in[12];
  const float* bih_r  = (const float*)d_in[13];
  const float* bhh_r  = (const float*)d_in[14];
  float* out = (float*)d_out;
  float* ws = (float*)d_ws;
  float* x     = ws + WS_X;
  float* xproj = ws + WS_XPROJ;
  float* Wt    = ws + WS_WT;
  float* linT  = ws + WS_LINT;
  float* sync  = ws + WS_SYNC;

  prep_kernel<<<768, 256, 0, stream>>>(conv_w, lin_w, Wt, linT, sync);
  charcnn_kernel<<<SQ, 256, 0, stream>>>(wemb, cidx, cemb, Wt, conv_b, linT, lin_b, x);
  xproj_kernel<<<dim3(64, 32, 2), 256, 0, stream>>>(x, Wih_f, Wih_r, bih_f, bhh_f, bih_r, bhh_r, xproj);
  lstm_kernel<<<64, 1024, 0, stream>>>(xproj, Whh_f, Whh_r, (u64*)sync, out);
}

// Round 16
// 7453.090 us; speedup vs baseline: 2.6371x; 2.6371x over previous
//
#include <hip/hip_runtime.h>
#include <cstdint>

#define SQ 4096
#define FD 256
#define HD 512
#define GD 2048

// workspace layout (float elements)
#define WS_X       0                         // x [4096][512]
#define WS_XPROJ   (WS_X + SQ*HD)            // xproj [2][4096][2048]
#define WS_WT      (WS_XPROJ + 2*SQ*GD)      // conv_w transposed [2][256][256]
#define WS_LINT    (WS_WT + 2*FD*FD)         // lin_w transposed [256][256]
#define WS_SYNC    (WS_LINT + FD*FD)         // payload: u64[2 dir][2 slot][512] = 16 KB

typedef __attribute__((ext_vector_type(4))) float f32x4;
typedef unsigned long long u64;

__device__ __forceinline__ float sigf(float x) { return 1.f / (1.f + __expf(-x)); }
// tanh(x) = 2*sigmoid(2x) - 1  (one __expf; |err| ~1e-7)
__device__ __forceinline__ float tanh_s(float x) { return fmaf(2.f, sigf(2.f * x), -1.f); }

#define REP8(M) M(0)M(1)M(2)M(3)M(4)M(5)M(6)M(7)

// ---------------- prep: transpose small weights, zero sync payload ----------------
__global__ __launch_bounds__(256) void prep_kernel(const float* __restrict__ conv_w,
                                                   const float* __restrict__ lin_w,
                                                   float* __restrict__ Wt,
                                                   float* __restrict__ linT,
                                                   float* __restrict__ sync) {
  int n = blockIdx.x * 256 + threadIdx.x;
  if (n < 4096) sync[n] = 0.f;               // 16 KB payload (tags := 0)
  if (n < 2 * FD * FD) {
    int o = n & 255, f = (n >> 8) & 255, k = n >> 16;
    Wt[n] = conv_w[o * 512 + k * 256 + f];   // Wt[k][f][o]
  } else {
    int m = n - 2 * FD * FD;
    int o = m & 255, f = m >> 8;
    linT[m] = lin_w[o * 256 + f];            // linT[f][o]
  }
}

// ---------------- char CNN + concat into x ----------------
__global__ __launch_bounds__(256) void charcnn_kernel(const float* __restrict__ wemb,
    const int* __restrict__ cidx, const float* __restrict__ cemb,
    const float* __restrict__ Wt, const float* __restrict__ conv_b,
    const float* __restrict__ linT, const float* __restrict__ lin_b,
    float* __restrict__ x) {
  __shared__ float ceT[256][20];
  __shared__ float pooled[256];
  int s = blockIdx.x, o = threadIdx.x;
  #pragma unroll
  for (int l = 0; l < 16; ++l) {
    int idx = cidx[s * 16 + l];
    ceT[o][l] = cemb[idx * 256 + o];
  }
  __syncthreads();
  float acc[15];
  float cb = conv_b[o];
  #pragma unroll
  for (int l = 0; l < 15; ++l) acc[l] = cb;
  for (int f = 0; f < 256; ++f) {
    float w0 = Wt[f * 256 + o];
    float w1 = Wt[65536 + f * 256 + o];
    float4 ca = *(const float4*)&ceT[f][0];
    float4 cv = *(const float4*)&ceT[f][4];
    float4 cc = *(const float4*)&ceT[f][8];
    float4 cd = *(const float4*)&ceT[f][12];
    float c[16] = {ca.x, ca.y, ca.z, ca.w, cv.x, cv.y, cv.z, cv.w,
                   cc.x, cc.y, cc.z, cc.w, cd.x, cd.y, cd.z, cd.w};
    #pragma unroll
    for (int l = 0; l < 15; ++l) acc[l] += c[l] * w0 + c[l + 1] * w1;
  }
  float m = 0.f;
  #pragma unroll
  for (int l = 0; l < 15; ++l) m = fmaxf(m, acc[l]);
  pooled[o] = m;
  __syncthreads();
  float a2 = lin_b[o];
  for (int f = 0; f < 256; f += 4) {
    float4 p = *(const float4*)&pooled[f];
    a2 += p.x * linT[(f + 0) * 256 + o] + p.y * linT[(f + 1) * 256 + o]
        + p.z * linT[(f + 2) * 256 + o] + p.w * linT[(f + 3) * 256 + o];
  }
  x[(size_t)s * 512 + o] = wemb[(size_t)s * 256 + o];
  x[(size_t)s * 512 + 256 + o] = a2;
}

// ---------------- input projection GEMM ----------------
__global__ __launch_bounds__(256) void xproj_kernel(const float* __restrict__ x,
    const float* __restrict__ Wih_f, const float* __restrict__ Wih_r,
    const float* __restrict__ bih_f, const float* __restrict__ bhh_f,
    const float* __restrict__ bih_r, const float* __restrict__ bhh_r,
    float* __restrict__ xproj) {
  __shared__ float As[64][33];
  __shared__ float Bs[64][33];
  int dir = blockIdx.z;
  const float* B  = dir ? Wih_r : Wih_f;
  const float* b1 = dir ? bih_r : bih_f;
  const float* b2 = dir ? bhh_r : bhh_f;
  int m0 = blockIdx.x * 64, n0 = blockIdx.y * 64;
  int tid = threadIdx.x, tx = tid & 15, ty = tid >> 4;
  float acc[4][4];
  #pragma unroll
  for (int j = 0; j < 4; ++j) {
    float bias = b1[n0 + tx * 4 + j] + b2[n0 + tx * 4 + j];
    #pragma unroll
    for (int i = 0; i < 4; ++i) acc[i][j] = bias;
  }
  int lc = tid & 31, lr0 = tid >> 5;
  for (int k0 = 0; k0 < 512; k0 += 32) {
    #pragma unroll
    for (int i = 0; i < 8; ++i) {
      As[lr0 + 8 * i][lc] = x[(size_t)(m0 + lr0 + 8 * i) * 512 + k0 + lc];
      Bs[lr0 + 8 * i][lc] = B[(size_t)(n0 + lr0 + 8 * i) * 512 + k0 + lc];
    }
    __syncthreads();
    #pragma unroll
    for (int kk = 0; kk < 32; ++kk) {
      float a0 = As[ty * 4 + 0][kk], a1 = As[ty * 4 + 1][kk];
      float a2 = As[ty * 4 + 2][kk], a3 = As[ty * 4 + 3][kk];
      float q0 = Bs[tx * 4 + 0][kk], q1 = Bs[tx * 4 + 1][kk];
      float q2 = Bs[tx * 4 + 2][kk], q3 = Bs[tx * 4 + 3][kk];
      acc[0][0] += a0 * q0; acc[0][1] += a0 * q1; acc[0][2] += a0 * q2; acc[0][3] += a0 * q3;
      acc[1][0] += a1 * q0; acc[1][1] += a1 * q1; acc[1][2] += a1 * q2; acc[1][3] += a1 * q3;
      acc[2][0] += a2 * q0; acc[2][1] += a2 * q1; acc[2][2] += a2 * q2; acc[2][3] += a2 * q3;
      acc[3][0] += a3 * q0; acc[3][1] += a3 * q1; acc[3][2] += a3 * q2; acc[3][3] += a3 * q3;
    }
    __syncthreads();
  }
  size_t base = (size_t)dir * SQ * GD;
  #pragma unroll
  for (int i = 0; i < 4; ++i) {
    float4 v = make_float4(acc[i][0], acc[i][1], acc[i][2], acc[i][3]);
    *(float4*)&xproj[base + (size_t)(m0 + ty * 4 + i) * GD + n0 + tx * 4] = v;
  }
}

// ---------------- persistent bidirectional LSTM recurrence ----------------
// EXACT round-14 kernel (measured best: 6.66 ms steady / 7.50 ms total).
// r15's asm-prefetch variant spilled (VGPR=36, scratch on critical path) --
// reverted. 64 blocks x 1024 threads: 0..31 fwd, 32..63 rev; block owns 16 h
// (64 rows). Wave w (0..15) owns h-index j=w: lane = gate*16 + kq.
// Payload: ONE u64 per h per slot = (tag<<32)|h_bits (no tearing; single poll
// load per round). Double slot; monotone tags; RMW publish.
// Step = stage(LDS, dbuf) -> ONE barrier -> in-wave GEMV + shfl reduce +
// parallel activations at kq==0 lanes + lane-0 gather/c,h -> publish.
// LDS dbuf safety (1 barrier): stage at t+2 reuses buf of t; fast wave passed
// barrier(t+1) which required all waves done staging t+1, which follows their
// step-t GEMV reads -- so no wave still reads buf when overwritten.
// Global overwrite safety (r4 proof, wave-sliced form): each wave's 16-lane
// kq group covers ALL of K, so ANY wave publishing tag t+1 implies its block
// passed barrier t+1, i.e. its stagers saw tag t on ALL 512 words, i.e. every
// block published t and is done reading tag t-1 from the slot being reused.
__global__ __launch_bounds__(1024, 4) void lstm_kernel(const float* __restrict__ xproj,
    const float* __restrict__ Whh_f, const float* __restrict__ Whh_r,
    u64* __restrict__ payu, float* __restrict__ out) {
  __shared__ float hl[2][16 * 36];   // double-buffered h: 16 kq-slices of 32, pitch 36
  int dir = blockIdx.x >> 5;
  int wid = blockIdx.x & 31;
  int hbase = wid * 16;
  int tid = threadIdx.x;
  int w = tid >> 6, lane = tid & 63;
  int gate = lane >> 4, kq = lane & 15;
  int Rrow = (gate << 9) + hbase + w;              // gate*512 + hbase + j(=w)
  const float* Whh = dir ? Whh_r : Whh_f;
  const float* xp = xproj + (size_t)dir * SQ * GD;
  const f32x4* wsrc4 = (const f32x4*)(Whh + (size_t)Rrow * 512 + kq * 32);
#define LDW(i) f32x4 w##i = wsrc4[i];
  REP8(LDW)
#undef LDW
#define PIN(i) asm volatile("" : "+v"(w##i));
  REP8(PIN)
#undef PIN
  u64* mypay = payu + (size_t)dir * 1024;          // [slot][512]

  const bool lz = (lane == 0);                     // gate lane of wave w
  float cst = 0.f, hlast = 0.f;

  for (int t = 0; t < SQ; ++t) {
    int p = dir ? (SQ - 1 - t) : t;
    float xval = 0.f;
    if (kq == 0) xval = xp[(size_t)p * GD + Rrow]; // issued early, in flight
    int buf = (t + 1) & 1;                         // stage h(t-1) into this buf
    if (tid < 512) {                               // stager: one u64 word each
      float hv;
      if (t == 0) hv = 0.f;
      else {
        const u64* src = mypay + ((t - 1) & 1) * 512 + tid;
        unsigned tg = (unsigned)t;
        u64 v;
        do { v = __hip_atomic_load(src, __ATOMIC_RELAXED, __HIP_MEMORY_SCOPE_AGENT); }
        while ((unsigned)(v >> 32) != tg);
        hv = __uint_as_float((unsigned)v);
      }
      hl[buf][(tid >> 5) * 36 + (tid & 31)] = hv;
    }
    __syncthreads();                               // h ready (sole barrier)
    float a0 = 0.f, a1 = 0.f, a2 = 0.f, a3 = 0.f;
    const f32x4* hq4 = (const f32x4*)&hl[buf][kq * 36];
#define GST(i) { f32x4 hh = hq4[i]; \
    a0 = fmaf(w##i[0], hh[0], a0); a1 = fmaf(w##i[1], hh[1], a1); \
    a2 = fmaf(w##i[2], hh[2], a2); a3 = fmaf(w##i[3], hh[3], a3); }
    REP8(GST)
#undef GST
    float acc = (a0 + a1) + (a2 + a3);
    acc += __shfl_xor(acc, 1);                     // kq reduce (16 lanes)
    acc += __shfl_xor(acc, 2);
    acc += __shfl_xor(acc, 4);
    acc += __shfl_xor(acc, 8);
    float gx = acc + xval;                         // valid at kq==0 lanes
    // parallel activation at the 4 kq==0 lanes (gate 2 = tanh, else sigmoid)
    float act = (gate == 2) ? tanh_s(gx) : sigf(gx);
    float aI = __shfl(act, 0);                     // in-wave gather (full wave)
    float aF = __shfl(act, 16);
    float aG = __shfl(act, 32);
    float aO = __shfl(act, 48);
    if (lz) {
      float c = aF * cst + aI * aG;
      float hval = aO * tanh_s(c);
      cst = c; hlast = hval;
      // publish FIRST (RMW executes at coherence point), then output store
      u64 word = ((u64)(unsigned)(t + 1) << 32) | __float_as_uint(hval);
      u64 old = __hip_atomic_exchange(mypay + (t & 1) * 512 + hbase + w, word,
                                      __ATOMIC_RELAXED, __HIP_MEMORY_SCOPE_AGENT);
      asm volatile("" :: "v"(old));
      out[(size_t)p * 1024 + dir * 512 + hbase + w] = hval;
    }
  }
  if (lz) {
    size_t OH = (size_t)SQ * 1024;
    out[OH + dir * 512 + hbase + w] = hlast;       // hidden
    out[OH + 1024 + dir * 512 + hbase + w] = cst;  // cell
  }
}

extern "C" void kernel_launch(void* const* d_in, const int* in_sizes, int n_in,
                              void* d_out, int out_size, void* d_ws, size_t ws_size,
                              hipStream_t stream) {
  const float* wemb   = (const float*)d_in[0];
  const int*   cidx   = (const int*)d_in[1];
  const float* cemb   = (const float*)d_in[2];
  const float* conv_w = (const float*)d_in[3];
  const float* conv_b = (const float*)d_in[4];
  const float* lin_w  = (const float*)d_in[5];
  const float* lin_b  = (const float*)d_in[6];
  const float* Wih_f  = (const float*)d_in[7];
  const float* Whh_f  = (const float*)d_in[8];
  const float* bih_f  = (const float*)d_in[9];
  const float* bhh_f  = (const float*)d_in[10];
  const float* Wih_r  = (const float*)d_in[11];
  const float* Whh_r  = (const float*)d_in[12];
  const float* bih_r  = (const float*)d_in[13];
  const float* bhh_r  = (const float*)d_in[14];
  float* out = (float*)d_out;
  float* ws = (float*)d_ws;
  float* x     = ws + WS_X;
  float* xproj = ws + WS_XPROJ;
  float* Wt    = ws + WS_WT;
  float* linT  = ws + WS_LINT;
  float* sync  = ws + WS_SYNC;

  prep_kernel<<<768, 256, 0, stream>>>(conv_w, lin_w, Wt, linT, sync);
  charcnn_kernel<<<SQ, 256, 0, stream>>>(wemb, cidx, cemb, Wt, conv_b, linT, lin_b, x);
  xproj_kernel<<<dim3(64, 32, 2), 256, 0, stream>>>(x, Wih_f, Wih_r, bih_f, bhh_f, bih_r, bhh_r, xproj);
  lstm_kernel<<<64, 1024, 0, stream>>>(xproj, Whh_f, Whh_r, (u64*)sync, out);
}